// Round 2
// baseline (274.947 us; speedup 1.0000x reference)
//
#include <hip/hip_runtime.h>
#include <stdint.h>

#define Bn 256
#define Tn 50
#define Mn 20
#define En 128
#define G3 384   // 3*E

__device__ __forceinline__ float sigmoidf(float x) {
    return 1.0f / (1.0f + __expf(-x));
}
__device__ __forceinline__ float tanh_safe(float a) {
    float ax = fabsf(a);
    float e2 = __expf(-2.0f * ax);
    float th = (1.0f - e2) / (1.0f + e2);
    return copysignf(th, a);
}

// One block per batch row b; 384 threads (thread j owns gate row j).
// Phase 1: basket-mean embedding -> ub[50][128] in LDS.
// Phase 2: xg[t][j] = b_ih[j] + dot(W_ih[j,:], ub[t])   (W_ih row in regs)
// Phase 3: 50-step GRU, W_hh row in the same regs, h in LDS.
__global__ __launch_bounds__(384, 2) void drmodel_fused(
    const int*   __restrict__ item_ids,      // [B*T*M]
    const int*   __restrict__ basket_sizes,  // [B*T]
    const int*   __restrict__ lengths,       // [B]
    const float* __restrict__ emb,           // [(V+2)*E]
    const float* __restrict__ W_ih,          // [3E*E]
    const float* __restrict__ W_hh,          // [3E*E]
    const float* __restrict__ b_ih,          // [3E]
    const float* __restrict__ b_hh,          // [3E]
    const float* __restrict__ h0,            // [B*E]
    float* __restrict__ out_dyn,             // [B*T*E]
    float* __restrict__ out_h)               // [B*E]
{
    __shared__ float ub[Tn][En];     // 25.6 KB
    __shared__ float xg[Tn][G3];     // 76.8 KB
    __shared__ float h[En];
    __shared__ float s[G3];

    const int tid = threadIdx.x;
    const int b   = blockIdx.x;

    // ---- W_ih row tid into registers (32 float4 = 128 VGPRs) ----
    float4 w[32];
    {
        const float4* wr = (const float4*)(W_ih + (size_t)tid * En);
        #pragma unroll
        for (int c = 0; c < 32; ++c) w[c] = wr[c];
    }

    // ---- phase 1: gather + mean into ub ----
    for (int slot = tid; slot < Tn * 32; slot += 384) {
        const int t = slot >> 5, lane = slot & 31;
        const int* ids = item_ids + ((size_t)b * Tn + t) * Mn;
        float ax = 0.f, ay = 0.f, az = 0.f, aw = 0.f;
        #pragma unroll
        for (int m = 0; m < Mn; ++m) {
            const float4 e4 = *(const float4*)(emb + (size_t)ids[m] * En + lane * 4);
            ax += e4.x; ay += e4.y; az += e4.z; aw += e4.w;
        }
        const float inv = 1.0f / (float)basket_sizes[b * Tn + t];
        *(float4*)&ub[t][lane * 4] = make_float4(ax * inv, ay * inv, az * inv, aw * inv);
    }
    const float bi = b_ih[tid];
    __syncthreads();

    // ---- phase 2: xg = ub @ W_ih^T + b_ih ----
    for (int t = 0; t < Tn; ++t) {
        const float4* u4 = (const float4*)ub[t];
        float a0 = 0.f, a1 = 0.f, a2 = 0.f, a3 = 0.f;
        #pragma unroll
        for (int c = 0; c < 32; c += 4) {
            float4 u0 = u4[c+0], u1 = u4[c+1], u2 = u4[c+2], u3 = u4[c+3];
            a0 = fmaf(w[c+0].x,u0.x,a0); a0 = fmaf(w[c+0].y,u0.y,a0);
            a0 = fmaf(w[c+0].z,u0.z,a0); a0 = fmaf(w[c+0].w,u0.w,a0);
            a1 = fmaf(w[c+1].x,u1.x,a1); a1 = fmaf(w[c+1].y,u1.y,a1);
            a1 = fmaf(w[c+1].z,u1.z,a1); a1 = fmaf(w[c+1].w,u1.w,a1);
            a2 = fmaf(w[c+2].x,u2.x,a2); a2 = fmaf(w[c+2].y,u2.y,a2);
            a2 = fmaf(w[c+2].z,u2.z,a2); a2 = fmaf(w[c+2].w,u2.w,a2);
            a3 = fmaf(w[c+3].x,u3.x,a3); a3 = fmaf(w[c+3].y,u3.y,a3);
            a3 = fmaf(w[c+3].z,u3.z,a3); a3 = fmaf(w[c+3].w,u3.w,a3);
        }
        xg[t][tid] = bi + ((a0 + a1) + (a2 + a3));
    }

    // ---- swap to W_hh row tid (same registers) ----
    {
        const float4* wr = (const float4*)(W_hh + (size_t)tid * En);
        #pragma unroll
        for (int c = 0; c < 32; ++c) w[c] = wr[c];
    }
    const float bh = b_hh[tid];
    if (tid < En) h[tid] = h0[(size_t)b * En + tid];
    const int len = lengths[b];
    float* outb = out_dyn + (size_t)b * Tn * En;
    __syncthreads();

    // ---- phase 3: sequential GRU ----
    for (int t = 0; t < len; ++t) {
        const float4* h4 = (const float4*)h;
        float a0 = 0.f, a1 = 0.f, a2 = 0.f, a3 = 0.f;
        #pragma unroll
        for (int c = 0; c < 32; c += 4) {
            float4 u0 = h4[c+0], u1 = h4[c+1], u2 = h4[c+2], u3 = h4[c+3];
            a0 = fmaf(w[c+0].x,u0.x,a0); a0 = fmaf(w[c+0].y,u0.y,a0);
            a0 = fmaf(w[c+0].z,u0.z,a0); a0 = fmaf(w[c+0].w,u0.w,a0);
            a1 = fmaf(w[c+1].x,u1.x,a1); a1 = fmaf(w[c+1].y,u1.y,a1);
            a1 = fmaf(w[c+1].z,u1.z,a1); a1 = fmaf(w[c+1].w,u1.w,a1);
            a2 = fmaf(w[c+2].x,u2.x,a2); a2 = fmaf(w[c+2].y,u2.y,a2);
            a2 = fmaf(w[c+2].z,u2.z,a2); a2 = fmaf(w[c+2].w,u2.w,a2);
            a3 = fmaf(w[c+3].x,u3.x,a3); a3 = fmaf(w[c+3].y,u3.y,a3);
            a3 = fmaf(w[c+3].z,u3.z,a3); a3 = fmaf(w[c+3].w,u3.w,a3);
        }
        float hg = bh + ((a0 + a1) + (a2 + a3));
        // s: r/z slots carry x+h; n slot carries h-gate only (xn added later)
        s[tid] = (tid < 2 * En) ? (xg[t][tid] + hg) : hg;
        __syncthreads();

        if (tid < En) {
            const float r  = sigmoidf(s[tid]);
            const float z  = sigmoidf(s[En + tid]);
            const float hn = s[2 * En + tid];
            const float xn = xg[t][2 * En + tid];
            const float n  = tanh_safe(xn + r * hn);
            const float hnew = (1.0f - z) * n + z * h[tid];
            h[tid] = hnew;
            outb[t * En + tid] = hnew;
        }
        __syncthreads();
    }
    // masked-out steps -> 0
    for (int t = len; t < Tn; ++t)
        if (tid < En) outb[t * En + tid] = 0.0f;
    if (tid < En) out_h[(size_t)b * En + tid] = h[tid];
}

extern "C" void kernel_launch(void* const* d_in, const int* in_sizes, int n_in,
                              void* d_out, int out_size, void* d_ws, size_t ws_size,
                              hipStream_t stream) {
    const int*   item_ids     = (const int*)d_in[0];
    const int*   basket_sizes = (const int*)d_in[1];
    const int*   lengths      = (const int*)d_in[2];
    const float* emb          = (const float*)d_in[3];
    const float* W_ih         = (const float*)d_in[4];
    const float* W_hh         = (const float*)d_in[5];
    const float* b_ih         = (const float*)d_in[6];
    const float* b_hh         = (const float*)d_in[7];
    const float* h0           = (const float*)d_in[8];
    float* out = (float*)d_out;

    drmodel_fused<<<Bn, 384, 0, stream>>>(
        item_ids, basket_sizes, lengths, emb, W_ih, W_hh, b_ih, b_hh, h0,
        out, out + (size_t)Bn * Tn * En);
}